// Round 1
// baseline (738.653 us; speedup 1.0000x reference)
//
#include <hip/hip_runtime.h>
#include <math.h>

// ---------------------------------------------------------------------------
// GAT encoder, 2 layers, fp32 throughout.
//   layer: h = A @ W; a_s/a_d = per-head dots; e = leaky(a_s[src]+a_d[dst]);
//          alpha = segment_softmax(e, dst); out = elu(seg_sum(alpha*h[src]) + b)
// CSR-by-dst built once per launch (same edges both layers); aggregation is a
// gather per dst node with lane-local online softmax (no atomics, no LDS).
// ---------------------------------------------------------------------------

#define LEAKY_SLOPE 0.2f

// ---------------- CSR build ----------------

__global__ void hist_kernel(const int* __restrict__ ei, int* __restrict__ cnt,
                            int E, int Etot) {
    int e = blockIdx.x * blockDim.x + threadIdx.x;
    if (e >= Etot) return;
    int dst = (e < E) ? ei[E + e] : (e - E);
    atomicAdd(&cnt[dst], 1);
}

__global__ __launch_bounds__(1024) void scan_kernel(const int* __restrict__ cnt,
                                                    int* __restrict__ row_start,
                                                    int n) {
    __shared__ int sdata[1024];
    __shared__ int carry_s;
    int tid = threadIdx.x;
    if (tid == 0) carry_s = 0;
    __syncthreads();
    const int CH = 8192;  // 1024 threads x 8 elements
    for (int base = 0; base < n; base += CH) {
        int idx0 = base + tid * 8;
        int v[8];
#pragma unroll
        for (int j = 0; j < 8; j++) {
            int i = idx0 + j;
            v[j] = (i < n) ? cnt[i] : 0;
        }
        int tot = 0;
#pragma unroll
        for (int j = 0; j < 8; j++) { int t = v[j]; v[j] = tot; tot += t; }
        sdata[tid] = tot;
        __syncthreads();
        int x = tot;
        for (int off = 1; off < 1024; off <<= 1) {
            int y = (tid >= off) ? sdata[tid - off] : 0;
            __syncthreads();
            x += y;
            sdata[tid] = x;
            __syncthreads();
        }
        int carry = carry_s;
        __syncthreads();
        if (tid == 1023) carry_s = carry + x;
        int base_excl = carry + x - tot;  // exclusive prefix of this thread's chunk
#pragma unroll
        for (int j = 0; j < 8; j++) {
            int i = idx0 + j;
            if (i < n) row_start[i] = base_excl + v[j];
        }
        __syncthreads();
    }
    if (tid == 0) row_start[n] = carry_s;
}

__global__ void scatter_kernel(const int* __restrict__ ei,
                               const int* __restrict__ row_start,
                               int* __restrict__ fill,
                               int* __restrict__ edge_src, int E, int Etot) {
    int e = blockIdx.x * blockDim.x + threadIdx.x;
    if (e >= Etot) return;
    int src, dst;
    if (e < E) { src = ei[e]; dst = ei[E + e]; }
    else       { src = e - E; dst = e - E; }
    int pos = row_start[dst] + atomicAdd(&fill[dst], 1);
    edge_src[pos] = src;
}

// ---------------- SGEMM: C[M,256] = A[M,K] @ B[K,256] ----------------
// 128x128 block tile, 256 threads, 8x8 per thread, BK=16.

template <int K>
__global__ __launch_bounds__(256) void sgemm(const float* __restrict__ A,
                                             const float* __restrict__ B,
                                             float* __restrict__ C, int M) {
    constexpr int BK = 16;
    __shared__ float As[BK][132];  // transposed A tile, +4 pad (keeps 16B align)
    __shared__ float Bs[BK][132];

    int bx = blockIdx.x & 1;        // 256/128 = 2 col tiles
    int by = blockIdx.x >> 1;
    int row0 = by * 128, col0 = bx * 128;
    int tid = threadIdx.x;
    int tx = tid & 15, ty = tid >> 4;

    float acc[8][8] = {};

    for (int k0 = 0; k0 < K; k0 += BK) {
#pragma unroll
        for (int i = 0; i < 2; i++) {
            int t = tid + i * 256;
            int ar = t >> 2;           // 0..127
            int ak = (t & 3) * 4;      // 0,4,8,12
            float4 v = {0.f, 0.f, 0.f, 0.f};
            int gr = row0 + ar;
            if (gr < M) v = *(const float4*)&A[(size_t)gr * K + k0 + ak];
            As[ak][ar] = v.x; As[ak + 1][ar] = v.y;
            As[ak + 2][ar] = v.z; As[ak + 3][ar] = v.w;
        }
#pragma unroll
        for (int i = 0; i < 2; i++) {
            int t = tid + i * 256;
            int kk = t >> 5;           // 0..15
            int c4 = (t & 31) * 4;     // 0..124
            float4 v = *(const float4*)&B[(size_t)(k0 + kk) * 256 + col0 + c4];
            *(float4*)&Bs[kk][c4] = v;
        }
        __syncthreads();
#pragma unroll
        for (int k = 0; k < BK; k++) {
            float a[8], b[8];
            *(float4*)&a[0] = *(const float4*)&As[k][ty * 8];
            *(float4*)&a[4] = *(const float4*)&As[k][ty * 8 + 4];
            *(float4*)&b[0] = *(const float4*)&Bs[k][tx * 8];
            *(float4*)&b[4] = *(const float4*)&Bs[k][tx * 8 + 4];
#pragma unroll
            for (int i = 0; i < 8; i++)
#pragma unroll
                for (int j = 0; j < 8; j++) acc[i][j] += a[i] * b[j];
        }
        __syncthreads();
    }

#pragma unroll
    for (int i = 0; i < 8; i++) {
        int gr = row0 + ty * 8 + i;
        if (gr < M) {
            float4 v0 = {acc[i][0], acc[i][1], acc[i][2], acc[i][3]};
            float4 v1 = {acc[i][4], acc[i][5], acc[i][6], acc[i][7]};
            *(float4*)&C[(size_t)gr * 256 + col0 + tx * 8] = v0;
            *(float4*)&C[(size_t)gr * 256 + col0 + tx * 8 + 4] = v1;
        }
    }
}

// ---------------- attention dots: a_s/a_d [N,4] ----------------
// one wave per node; lane l: head = l>>4, channels 4l..4l+3

__global__ void attn_dots(const float* __restrict__ h,
                          const float* __restrict__ att_src,
                          const float* __restrict__ att_dst,
                          float* __restrict__ a_s, float* __restrict__ a_d,
                          int n) {
    int wave = (blockIdx.x * blockDim.x + threadIdx.x) >> 6;
    if (wave >= n) return;
    int lane = threadIdx.x & 63;
    float4 hv = *(const float4*)&h[(size_t)wave * 256 + lane * 4];
    float4 s4 = *(const float4*)&att_src[lane * 4];
    float4 d4 = *(const float4*)&att_dst[lane * 4];
    float s = hv.x * s4.x + hv.y * s4.y + hv.z * s4.z + hv.w * s4.w;
    float d = hv.x * d4.x + hv.y * d4.y + hv.z * d4.z + hv.w * d4.w;
#pragma unroll
    for (int off = 1; off < 16; off <<= 1) {
        s += __shfl_xor(s, off, 64);
        d += __shfl_xor(d, off, 64);
    }
    if ((lane & 15) == 0) {
        int head = lane >> 4;
        a_s[wave * 4 + head] = s;
        a_d[wave * 4 + head] = d;
    }
}

// ---------------- fused online-softmax + aggregate + bias + elu ----------------
// one wave per dst node; lane l owns head l>>4, channels 4l..4l+3 (lane-local
// softmax state, coalesced 1KB gather of h[src] per edge).

__global__ __launch_bounds__(256) void gat_aggregate(
    const float* __restrict__ h, const float* __restrict__ a_s,
    const float* __restrict__ a_d, const int* __restrict__ row_start,
    const int* __restrict__ edge_src, const float* __restrict__ bias,
    float* __restrict__ out, int n) {
    int node = (blockIdx.x * blockDim.x + threadIdx.x) >> 6;
    if (node >= n) return;
    int lane = threadIdx.x & 63;
    int head = lane >> 4;

    float ad = a_d[node * 4 + head];
    int beg = row_start[node], end = row_start[node + 1];

    float m = -3.4e38f, l = 0.f;
    float ax = 0.f, ay = 0.f, az = 0.f, aw = 0.f;

    for (int i = beg; i < end; ++i) {
        int s = edge_src[i];
        float e = a_s[s * 4 + head] + ad;
        e = (e > 0.f) ? e : LEAKY_SLOPE * e;
        float4 v = *(const float4*)&h[(size_t)s * 256 + lane * 4];
        float mn = fmaxf(m, e);
        float sc = __expf(m - mn);   // 0 on first iteration (m = -3.4e38)
        float w  = __expf(e - mn);
        l = l * sc + w;
        ax = ax * sc + w * v.x;
        ay = ay * sc + w * v.y;
        az = az * sc + w * v.z;
        aw = aw * sc + w * v.w;
        m = mn;
    }

    float r = 1.f / (l + 1e-16f);
    float4 b4 = *(const float4*)&bias[lane * 4];
    float ox = ax * r + b4.x;
    float oy = ay * r + b4.y;
    float oz = az * r + b4.z;
    float ow = aw * r + b4.w;
    // elu
    ox = (ox > 0.f) ? ox : __expf(ox) - 1.f;
    oy = (oy > 0.f) ? oy : __expf(oy) - 1.f;
    oz = (oz > 0.f) ? oz : __expf(oz) - 1.f;
    ow = (ow > 0.f) ? ow : __expf(ow) - 1.f;
    float4 o = {ox, oy, oz, ow};
    *(float4*)&out[(size_t)node * 256 + lane * 4] = o;
}

// ---------------- launch ----------------

extern "C" void kernel_launch(void* const* d_in, const int* in_sizes, int n_in,
                              void* d_out, int out_size, void* d_ws, size_t ws_size,
                              hipStream_t stream) {
    const float* x   = (const float*)d_in[0];
    const int*   ei  = (const int*)d_in[1];
    const float* W1  = (const float*)d_in[2];
    const float* as1 = (const float*)d_in[3];
    const float* ad1 = (const float*)d_in[4];
    const float* b1  = (const float*)d_in[5];
    const float* W2  = (const float*)d_in[6];
    const float* as2 = (const float*)d_in[7];
    const float* ad2 = (const float*)d_in[8];
    const float* b2  = (const float*)d_in[9];
    float* out = (float*)d_out;

    const int N = in_sizes[0] / 128;
    const int E = in_sizes[1] / 2;
    const int Etot = E + N;

    // workspace layout (fp32 elements)
    float* h_buf   = (float*)d_ws;                     // N*256
    float* x1_buf  = h_buf + (size_t)N * 256;          // N*256
    float* a_s     = x1_buf + (size_t)N * 256;         // N*4
    float* a_d     = a_s + (size_t)N * 4;              // N*4
    int*   cnt     = (int*)(a_d + (size_t)N * 4);      // N
    int*   fill    = cnt + N;                          // N
    int*   row_st  = fill + N;                         // N+1
    int*   edge_src= row_st + (N + 1);                 // Etot

    // CSR build (edges identical for both layers)
    hipMemsetAsync(cnt, 0, sizeof(int) * 2 * (size_t)N, stream);  // cnt + fill
    int eblocks = (Etot + 255) / 256;
    hist_kernel<<<eblocks, 256, 0, stream>>>(ei, cnt, E, Etot);
    scan_kernel<<<1, 1024, 0, stream>>>(cnt, row_st, N);
    scatter_kernel<<<eblocks, 256, 0, stream>>>(ei, row_st, fill, edge_src, E, Etot);

    dim3 ggrid(2 * ((N + 127) / 128));
    int nblocks = (N + 3) / 4;  // 4 waves (nodes) per 256-thread block

    // layer 1
    sgemm<128><<<ggrid, 256, 0, stream>>>(x, W1, h_buf, N);
    attn_dots<<<nblocks, 256, 0, stream>>>(h_buf, as1, ad1, a_s, a_d, N);
    gat_aggregate<<<nblocks, 256, 0, stream>>>(h_buf, a_s, a_d, row_st, edge_src,
                                               b1, x1_buf, N);
    // layer 2
    sgemm<256><<<ggrid, 256, 0, stream>>>(x1_buf, W2, h_buf, N);
    attn_dots<<<nblocks, 256, 0, stream>>>(h_buf, as2, ad2, a_s, a_d, N);
    gat_aggregate<<<nblocks, 256, 0, stream>>>(h_buf, a_s, a_d, row_st, edge_src,
                                               b2, out, N);
}

// Round 2
// 583.157 us; speedup vs baseline: 1.2666x; 1.2666x over previous
//
#include <hip/hip_runtime.h>
#include <math.h>

// ---------------------------------------------------------------------------
// GAT encoder, 2 layers.
//   GEMMs: split-bf16 MFMA (A_hi*B_hi + A_hi*B_lo + A_lo*B_hi) ~ fp32 accuracy
//   Aggregation: CSR-by-dst gather, lane-local softmax WITHOUT running max
//   (e is bounded, exp cannot overflow), 1-deep software prefetch.
// ---------------------------------------------------------------------------

#define LEAKY_SLOPE 0.2f

typedef __attribute__((ext_vector_type(8))) short short8v;   // 8 bf16
typedef __attribute__((ext_vector_type(4))) float float4v;

// ---------------- CSR build ----------------

__global__ void hist_kernel(const int* __restrict__ ei, int* __restrict__ cnt,
                            int E, int Etot) {
    int e = blockIdx.x * blockDim.x + threadIdx.x;
    if (e >= Etot) return;
    int dst = (e < E) ? ei[E + e] : (e - E);
    atomicAdd(&cnt[dst], 1);
}

__global__ __launch_bounds__(1024) void scan_kernel(const int* __restrict__ cnt,
                                                    int* __restrict__ row_start,
                                                    int n) {
    __shared__ int sdata[1024];
    __shared__ int carry_s;
    int tid = threadIdx.x;
    if (tid == 0) carry_s = 0;
    __syncthreads();
    const int CH = 8192;
    for (int base = 0; base < n; base += CH) {
        int idx0 = base + tid * 8;
        int v[8];
#pragma unroll
        for (int j = 0; j < 8; j++) {
            int i = idx0 + j;
            v[j] = (i < n) ? cnt[i] : 0;
        }
        int tot = 0;
#pragma unroll
        for (int j = 0; j < 8; j++) { int t = v[j]; v[j] = tot; tot += t; }
        sdata[tid] = tot;
        __syncthreads();
        int x = tot;
        for (int off = 1; off < 1024; off <<= 1) {
            int y = (tid >= off) ? sdata[tid - off] : 0;
            __syncthreads();
            x += y;
            sdata[tid] = x;
            __syncthreads();
        }
        int carry = carry_s;
        __syncthreads();
        if (tid == 1023) carry_s = carry + x;
        int base_excl = carry + x - tot;
#pragma unroll
        for (int j = 0; j < 8; j++) {
            int i = idx0 + j;
            if (i < n) row_start[i] = base_excl + v[j];
        }
        __syncthreads();
    }
    if (tid == 0) row_start[n] = carry_s;
}

__global__ void scatter_kernel(const int* __restrict__ ei,
                               const int* __restrict__ row_start,
                               int* __restrict__ fill,
                               int* __restrict__ edge_src, int E, int Etot) {
    int e = blockIdx.x * blockDim.x + threadIdx.x;
    if (e >= Etot) return;
    int src, dst;
    if (e < E) { src = ei[e]; dst = ei[E + e]; }
    else       { src = e - E; dst = e - E; }
    int pos = row_start[dst] + atomicAdd(&fill[dst], 1);
    edge_src[pos] = src;
}

// ---------------- split-bf16 MFMA GEMM: C[M,256] = A[M,K] @ B[K,256] --------
// 128x128 block tile, BK=32, 256 threads = 2x2 waves, each wave 64x64 via
// 4x4 mfma_f32_16x16x32_bf16 tiles. A,B split to bf16 hi/lo during staging.

__device__ __forceinline__ void split_bf16(float f, short& hi, short& lo) {
    unsigned u = __float_as_uint(f);
    hi = (short)(u >> 16);
    float fhi = __uint_as_float(u & 0xFFFF0000u);
    float flo = f - fhi;                     // exact
    lo = (short)(__float_as_uint(flo) >> 16);
}

template <int K>
__global__ __launch_bounds__(256) void gemm_mfma(const float* __restrict__ A,
                                                 const float* __restrict__ B,
                                                 float* __restrict__ C, int M) {
    __shared__ short As_hi[128][40];   // [m][k], pad 32->40 (80B rows, 16B aligned)
    __shared__ short As_lo[128][40];
    __shared__ short Bs_hi[128][40];   // [n][k] (transposed)
    __shared__ short Bs_lo[128][40];

    const int col0 = (blockIdx.x & 1) * 128;
    const int row0 = (blockIdx.x >> 1) * 128;
    const int tid = threadIdx.x;
    const int lane = tid & 63;
    const int wave = tid >> 6;
    const int wr = wave >> 1, wc = wave & 1;
    const int quad = lane >> 4, lc = lane & 15;

    float4v acc[4][4] = {};

    const int bn = tid & 127;          // B-staging: column owned by this thread
    const int bkh = (tid >> 7) * 16;   // k-half 0 or 16

    for (int k0 = 0; k0 < K; k0 += 32) {
        // ---- stage A tile (128x32 fp32 -> hi/lo bf16) ----
#pragma unroll
        for (int i = 0; i < 4; i++) {
            int slot = tid + i * 256;       // 0..1023
            int r = slot >> 3;              // 0..127
            int kq = (slot & 7) * 4;        // 0..28
            float4 v = {0.f, 0.f, 0.f, 0.f};
            int gr = row0 + r;
            if (gr < M) v = *(const float4*)&A[(size_t)gr * K + k0 + kq];
            short4 h4, l4;
            split_bf16(v.x, h4.x, l4.x);
            split_bf16(v.y, h4.y, l4.y);
            split_bf16(v.z, h4.z, l4.z);
            split_bf16(v.w, h4.w, l4.w);
            *(short4*)&As_hi[r][kq] = h4;
            *(short4*)&As_lo[r][kq] = l4;
        }
        // ---- stage B tile (32x128 fp32 -> transposed hi/lo bf16) ----
        {
            float f[16];
#pragma unroll
            for (int j = 0; j < 16; j++)
                f[j] = B[(size_t)(k0 + bkh + j) * 256 + col0 + bn];
            short h8[16], l8[16];
#pragma unroll
            for (int j = 0; j < 16; j++) split_bf16(f[j], h8[j], l8[j]);
#pragma unroll
            for (int j = 0; j < 4; j++) {
                *(short4*)&Bs_hi[bn][bkh + j * 4] = *(short4*)&h8[j * 4];
                *(short4*)&Bs_lo[bn][bkh + j * 4] = *(short4*)&l8[j * 4];
            }
        }
        __syncthreads();

        // ---- fragments + MFMA ----
        short8v a_hi[4], a_lo[4], b_hi[4], b_lo[4];
#pragma unroll
        for (int mt = 0; mt < 4; mt++) {
            int r = wr * 64 + mt * 16 + lc;
            a_hi[mt] = *(const short8v*)&As_hi[r][quad * 8];
            a_lo[mt] = *(const short8v*)&As_lo[r][quad * 8];
        }
#pragma unroll
        for (int nt = 0; nt < 4; nt++) {
            int n = wc * 64 + nt * 16 + lc;
            b_hi[nt] = *(const short8v*)&Bs_hi[n][quad * 8];
            b_lo[nt] = *(const short8v*)&Bs_lo[n][quad * 8];
        }
#pragma unroll
        for (int mt = 0; mt < 4; mt++)
#pragma unroll
            for (int nt = 0; nt < 4; nt++) {
                acc[mt][nt] = __builtin_amdgcn_mfma_f32_16x16x32_bf16(
                    a_hi[mt], b_hi[nt], acc[mt][nt], 0, 0, 0);
                acc[mt][nt] = __builtin_amdgcn_mfma_f32_16x16x32_bf16(
                    a_hi[mt], b_lo[nt], acc[mt][nt], 0, 0, 0);
                acc[mt][nt] = __builtin_amdgcn_mfma_f32_16x16x32_bf16(
                    a_lo[mt], b_hi[nt], acc[mt][nt], 0, 0, 0);
            }
        __syncthreads();
    }

    // ---- epilogue: C/D layout col=lane&15, row=quad*4+reg ----
#pragma unroll
    for (int mt = 0; mt < 4; mt++) {
#pragma unroll
        for (int r = 0; r < 4; r++) {
            int gr = row0 + wr * 64 + mt * 16 + quad * 4 + r;
            if (gr < M) {
#pragma unroll
                for (int nt = 0; nt < 4; nt++) {
                    C[(size_t)gr * 256 + col0 + wc * 64 + nt * 16 + lc] =
                        acc[mt][nt][r];
                }
            }
        }
    }
}

// ---------------- attention dots: a_s/a_d [N,4] ----------------

__global__ void attn_dots(const float* __restrict__ h,
                          const float* __restrict__ att_src,
                          const float* __restrict__ att_dst,
                          float* __restrict__ a_s, float* __restrict__ a_d,
                          int n) {
    int wave = (blockIdx.x * blockDim.x + threadIdx.x) >> 6;
    if (wave >= n) return;
    int lane = threadIdx.x & 63;
    float4 hv = *(const float4*)&h[(size_t)wave * 256 + lane * 4];
    float4 s4 = *(const float4*)&att_src[lane * 4];
    float4 d4 = *(const float4*)&att_dst[lane * 4];
    float s = hv.x * s4.x + hv.y * s4.y + hv.z * s4.z + hv.w * s4.w;
    float d = hv.x * d4.x + hv.y * d4.y + hv.z * d4.z + hv.w * d4.w;
#pragma unroll
    for (int off = 1; off < 16; off <<= 1) {
        s += __shfl_xor(s, off, 64);
        d += __shfl_xor(d, off, 64);
    }
    if ((lane & 15) == 0) {
        int head = lane >> 4;
        a_s[wave * 4 + head] = s;
        a_d[wave * 4 + head] = d;
    }
}

// ---------------- fused softmax + aggregate + bias + elu ----------------
// One wave per dst node; lane l owns head l>>4, channels 4l..4l+3.
// No running max (e bounded: |e| <~ 10, exp safe in fp32); 1-deep prefetch.

__global__ __launch_bounds__(256) void gat_aggregate(
    const float* __restrict__ h, const float* __restrict__ a_s,
    const float* __restrict__ a_d, const int* __restrict__ row_start,
    const int* __restrict__ edge_src, const float* __restrict__ bias,
    float* __restrict__ out, int n) {
    int node = (blockIdx.x * blockDim.x + threadIdx.x) >> 6;
    if (node >= n) return;
    int lane = threadIdx.x & 63;
    int head = lane >> 4;

    float ad = a_d[node * 4 + head];
    int beg = row_start[node], end = row_start[node + 1];

    float l = 0.f, ax = 0.f, ay = 0.f, az = 0.f, aw = 0.f;

    // prefetch edge 0 (every node has a self-loop, so beg < end)
    int s = edge_src[beg];
    float as_v = a_s[s * 4 + head];
    float4 v = *(const float4*)&h[(size_t)s * 256 + lane * 4];

    for (int i = beg;;) {
        int in = i + 1;
        int sn = s; float asn = as_v; float4 vn = v;
        if (in < end) {
            sn = edge_src[in];
            asn = a_s[sn * 4 + head];
            vn = *(const float4*)&h[(size_t)sn * 256 + lane * 4];
        }
        float e = as_v + ad;
        e = (e > 0.f) ? e : LEAKY_SLOPE * e;
        float w = __expf(e);
        l += w;
        ax = fmaf(w, v.x, ax);
        ay = fmaf(w, v.y, ay);
        az = fmaf(w, v.z, az);
        aw = fmaf(w, v.w, aw);
        if (in >= end) break;
        i = in; s = sn; as_v = asn; v = vn;
    }

    float r = 1.f / l;
    float4 b4 = *(const float4*)&bias[lane * 4];
    float ox = fmaf(ax, r, b4.x);
    float oy = fmaf(ay, r, b4.y);
    float oz = fmaf(az, r, b4.z);
    float ow = fmaf(aw, r, b4.w);
    ox = (ox > 0.f) ? ox : __expf(ox) - 1.f;
    oy = (oy > 0.f) ? oy : __expf(oy) - 1.f;
    oz = (oz > 0.f) ? oz : __expf(oz) - 1.f;
    ow = (ow > 0.f) ? ow : __expf(ow) - 1.f;
    float4 o = {ox, oy, oz, ow};
    *(float4*)&out[(size_t)node * 256 + lane * 4] = o;
}

// ---------------- launch ----------------

extern "C" void kernel_launch(void* const* d_in, const int* in_sizes, int n_in,
                              void* d_out, int out_size, void* d_ws, size_t ws_size,
                              hipStream_t stream) {
    const float* x   = (const float*)d_in[0];
    const int*   ei  = (const int*)d_in[1];
    const float* W1  = (const float*)d_in[2];
    const float* as1 = (const float*)d_in[3];
    const float* ad1 = (const float*)d_in[4];
    const float* b1  = (const float*)d_in[5];
    const float* W2  = (const float*)d_in[6];
    const float* as2 = (const float*)d_in[7];
    const float* ad2 = (const float*)d_in[8];
    const float* b2  = (const float*)d_in[9];
    float* out = (float*)d_out;

    const int N = in_sizes[0] / 128;
    const int E = in_sizes[1] / 2;
    const int Etot = E + N;

    float* h_buf   = (float*)d_ws;                     // N*256
    float* x1_buf  = h_buf + (size_t)N * 256;          // N*256
    float* a_s     = x1_buf + (size_t)N * 256;         // N*4
    float* a_d     = a_s + (size_t)N * 4;              // N*4
    int*   cnt     = (int*)(a_d + (size_t)N * 4);      // N
    int*   fill    = cnt + N;                          // N
    int*   row_st  = fill + N;                         // N+1
    int*   edge_src= row_st + (N + 1);                 // Etot

    hipMemsetAsync(cnt, 0, sizeof(int) * 2 * (size_t)N, stream);  // cnt + fill
    int eblocks = (Etot + 255) / 256;
    hist_kernel<<<eblocks, 256, 0, stream>>>(ei, cnt, E, Etot);
    scan_kernel<<<1, 1024, 0, stream>>>(cnt, row_st, N);
    scatter_kernel<<<eblocks, 256, 0, stream>>>(ei, row_st, fill, edge_src, E, Etot);

    dim3 ggrid(2 * ((N + 127) / 128));
    int nblocks = (N + 3) / 4;

    gemm_mfma<128><<<ggrid, 256, 0, stream>>>(x, W1, h_buf, N);
    attn_dots<<<nblocks, 256, 0, stream>>>(h_buf, as1, ad1, a_s, a_d, N);
    gat_aggregate<<<nblocks, 256, 0, stream>>>(h_buf, a_s, a_d, row_st, edge_src,
                                               b1, x1_buf, N);
    gemm_mfma<256><<<ggrid, 256, 0, stream>>>(x1_buf, W2, h_buf, N);
    attn_dots<<<nblocks, 256, 0, stream>>>(h_buf, as2, ad2, a_s, a_d, N);
    gat_aggregate<<<nblocks, 256, 0, stream>>>(h_buf, a_s, a_d, row_st, edge_src,
                                               b2, out, N);
}

// Round 3
// 513.223 us; speedup vs baseline: 1.4392x; 1.1363x over previous
//
#include <hip/hip_runtime.h>
#include <hip/hip_fp16.h>
#include <math.h>

// ---------------------------------------------------------------------------
// GAT encoder, 2 layers.
//   GEMMs: split-bf16 MFMA (hi*hi + hi*lo + lo*hi) ~ fp32 accuracy; epilogue
//          writes h in FP16 (halves gather traffic) and computes the per-head
//          attention dots a_s/a_d exactly from the fp32 accumulators.
//   Aggregation: CSR-by-dst gather of fp16 h, lane-local softmax w/o running
//   max (e bounded), 2-deep software prefetch. No atomics in the hot path.
// ---------------------------------------------------------------------------

#define LEAKY_SLOPE 0.2f

typedef __attribute__((ext_vector_type(8))) short short8v;   // 8 bf16
typedef __attribute__((ext_vector_type(4))) float float4v;

// ---------------- CSR build ----------------

__global__ void hist_kernel(const int* __restrict__ ei, int* __restrict__ cnt,
                            int E, int Etot) {
    int e = blockIdx.x * blockDim.x + threadIdx.x;
    if (e >= Etot) return;
    int dst = (e < E) ? ei[E + e] : (e - E);
    atomicAdd(&cnt[dst], 1);
}

__global__ __launch_bounds__(1024) void scan_kernel(const int* __restrict__ cnt,
                                                    int* __restrict__ row_start,
                                                    int n) {
    __shared__ int wtot[16];
    __shared__ int carry_s;
    int tid = threadIdx.x, lane = tid & 63, wid = tid >> 6;
    if (tid == 0) carry_s = 0;
    __syncthreads();
    const int CH = 8192;  // 1024 threads x 8
    for (int base = 0; base < n; base += CH) {
        int idx0 = base + tid * 8;
        int v[8];
#pragma unroll
        for (int j = 0; j < 8; j++) {
            int i = idx0 + j;
            v[j] = (i < n) ? cnt[i] : 0;
        }
        int tot = 0;
#pragma unroll
        for (int j = 0; j < 8; j++) { int t = v[j]; v[j] = tot; tot += t; }
        // wave-inclusive scan of per-thread totals
        int x = tot;
#pragma unroll
        for (int off = 1; off < 64; off <<= 1) {
            int y = __shfl_up(x, off, 64);
            if (lane >= off) x += y;
        }
        if (lane == 63) wtot[wid] = x;
        __syncthreads();
        if (wid == 0 && lane < 16) {
            int w = wtot[lane];
#pragma unroll
            for (int off = 1; off < 16; off <<= 1) {
                int y = __shfl_up(w, off, 16);
                if (lane >= off) w += y;
            }
            wtot[lane] = w;  // inclusive over waves
        }
        __syncthreads();
        int wave_prefix = (wid > 0) ? wtot[wid - 1] : 0;
        int carry = carry_s;
        int chunk_total = wtot[15];
        int thread_excl = carry + wave_prefix + (x - tot);
#pragma unroll
        for (int j = 0; j < 8; j++) {
            int i = idx0 + j;
            if (i < n) row_start[i] = thread_excl + v[j];
        }
        __syncthreads();
        if (tid == 1023) carry_s = carry + chunk_total;
        __syncthreads();
    }
    if (tid == 0) row_start[n] = carry_s;
}

__global__ void scatter_kernel(const int* __restrict__ ei,
                               const int* __restrict__ row_start,
                               int* __restrict__ fill,
                               int* __restrict__ edge_src, int E, int Etot) {
    int e = blockIdx.x * blockDim.x + threadIdx.x;
    if (e >= Etot) return;
    int src, dst;
    if (e < E) { src = ei[e]; dst = ei[E + e]; }
    else       { src = e - E; dst = e - E; }
    int pos = row_start[dst] + atomicAdd(&fill[dst], 1);
    edge_src[pos] = src;
}

// ---------------- split-bf16 MFMA GEMM + fused attention dots ---------------
// C[M,256] = A[M,K] @ B[K,256], C stored fp16. 128x128 tile, BK=32,
// 256 threads = 2x2 waves of 64x64 (4x4 mfma_f32_16x16x32_bf16).
// Each wave's 64 columns = exactly one head; epilogue computes
// a_s/a_d[row, head] from fp32 accs via quad shuffle reduction.

__device__ __forceinline__ void split_bf16(float f, short& hi, short& lo) {
    unsigned u = __float_as_uint(f);
    hi = (short)(u >> 16);
    float fhi = __uint_as_float(u & 0xFFFF0000u);
    float flo = f - fhi;  // exact
    lo = (short)(__float_as_uint(flo) >> 16);
}

template <int K>
__global__ __launch_bounds__(256) void gemm_mfma(
    const float* __restrict__ A, const float* __restrict__ B,
    __half* __restrict__ Ch, const float* __restrict__ att_src,
    const float* __restrict__ att_dst, float* __restrict__ a_s_out,
    float* __restrict__ a_d_out, int M) {
    __shared__ short As_hi[128][40];   // [m][k], pad 32->40
    __shared__ short As_lo[128][40];
    __shared__ short Bs_hi[128][40];   // [n][k] (transposed)
    __shared__ short Bs_lo[128][40];

    const int col0 = (blockIdx.x & 1) * 128;
    const int row0 = (blockIdx.x >> 1) * 128;
    const int tid = threadIdx.x;
    const int lane = tid & 63;
    const int wave = tid >> 6;
    const int wr = wave >> 1, wc = wave & 1;
    const int quad = lane >> 4, lc = lane & 15;

    float4v acc[4][4] = {};

    const int bn = tid & 127;
    const int bkh = (tid >> 7) * 16;

    for (int k0 = 0; k0 < K; k0 += 32) {
#pragma unroll
        for (int i = 0; i < 4; i++) {
            int slot = tid + i * 256;
            int r = slot >> 3;
            int kq = (slot & 7) * 4;
            float4 v = {0.f, 0.f, 0.f, 0.f};
            int gr = row0 + r;
            if (gr < M) v = *(const float4*)&A[(size_t)gr * K + k0 + kq];
            short4 h4, l4;
            split_bf16(v.x, h4.x, l4.x);
            split_bf16(v.y, h4.y, l4.y);
            split_bf16(v.z, h4.z, l4.z);
            split_bf16(v.w, h4.w, l4.w);
            *(short4*)&As_hi[r][kq] = h4;
            *(short4*)&As_lo[r][kq] = l4;
        }
        {
            float f[16];
#pragma unroll
            for (int j = 0; j < 16; j++)
                f[j] = B[(size_t)(k0 + bkh + j) * 256 + col0 + bn];
            short h8[16], l8[16];
#pragma unroll
            for (int j = 0; j < 16; j++) split_bf16(f[j], h8[j], l8[j]);
#pragma unroll
            for (int j = 0; j < 4; j++) {
                *(short4*)&Bs_hi[bn][bkh + j * 4] = *(short4*)&h8[j * 4];
                *(short4*)&Bs_lo[bn][bkh + j * 4] = *(short4*)&l8[j * 4];
            }
        }
        __syncthreads();

        short8v a_hi[4], a_lo[4], b_hi[4], b_lo[4];
#pragma unroll
        for (int mt = 0; mt < 4; mt++) {
            int r = wr * 64 + mt * 16 + lc;
            a_hi[mt] = *(const short8v*)&As_hi[r][quad * 8];
            a_lo[mt] = *(const short8v*)&As_lo[r][quad * 8];
        }
#pragma unroll
        for (int nt = 0; nt < 4; nt++) {
            int n = wc * 64 + nt * 16 + lc;
            b_hi[nt] = *(const short8v*)&Bs_hi[n][quad * 8];
            b_lo[nt] = *(const short8v*)&Bs_lo[n][quad * 8];
        }
#pragma unroll
        for (int mt = 0; mt < 4; mt++)
#pragma unroll
            for (int nt = 0; nt < 4; nt++) {
                acc[mt][nt] = __builtin_amdgcn_mfma_f32_16x16x32_bf16(
                    a_hi[mt], b_hi[nt], acc[mt][nt], 0, 0, 0);
                acc[mt][nt] = __builtin_amdgcn_mfma_f32_16x16x32_bf16(
                    a_hi[mt], b_lo[nt], acc[mt][nt], 0, 0, 0);
                acc[mt][nt] = __builtin_amdgcn_mfma_f32_16x16x32_bf16(
                    a_lo[mt], b_hi[nt], acc[mt][nt], 0, 0, 0);
            }
        __syncthreads();
    }

    // ---- epilogue: this wave's cols = head `head`; C/D layout:
    //      col = lane&15 (+nt*16), row = quad*4 + reg (+mt*16) ----
    const int head = (col0 >> 6) + wc;
    float as_c[4], ad_c[4];
#pragma unroll
    for (int nt = 0; nt < 4; nt++) {
        as_c[nt] = att_src[head * 64 + nt * 16 + lc];
        ad_c[nt] = att_dst[head * 64 + nt * 16 + lc];
    }

#pragma unroll
    for (int mt = 0; mt < 4; mt++) {
#pragma unroll
        for (int r = 0; r < 4; r++) {
            int gr = row0 + wr * 64 + mt * 16 + quad * 4 + r;
            float ps = 0.f, pd = 0.f;
#pragma unroll
            for (int nt = 0; nt < 4; nt++) {
                float c = acc[mt][nt][r];
                ps = fmaf(c, as_c[nt], ps);
                pd = fmaf(c, ad_c[nt], pd);
                if (gr < M)
                    Ch[(size_t)gr * 256 + col0 + wc * 64 + nt * 16 + lc] =
                        __float2half(c);
            }
#pragma unroll
            for (int off = 1; off < 16; off <<= 1) {
                ps += __shfl_xor(ps, off, 64);
                pd += __shfl_xor(pd, off, 64);
            }
            if (lc == 0 && gr < M) {
                a_s_out[gr * 4 + head] = ps;
                a_d_out[gr * 4 + head] = pd;
            }
        }
    }
}

// ---------------- fused softmax + aggregate + bias + elu ----------------
// One wave per dst node; lane l owns head l>>4, channels 4l..4l+3.
// fp16 h gather (8B/lane), fp32 math, 2-deep prefetch.

__global__ __launch_bounds__(256) void gat_aggregate(
    const __half* __restrict__ hh, const float* __restrict__ a_s,
    const float* __restrict__ a_d, const int* __restrict__ row_start,
    const int* __restrict__ edge_src, const float* __restrict__ bias,
    float* __restrict__ out, int n) {
    int node = (blockIdx.x * blockDim.x + threadIdx.x) >> 6;
    if (node >= n) return;
    int lane = threadIdx.x & 63;
    int head = lane >> 4;

    float ad = a_d[node * 4 + head];
    int beg = row_start[node], end = row_start[node + 1];

    float l = 0.f, ax = 0.f, ay = 0.f, az = 0.f, aw = 0.f;

    // 2-deep pipeline (every node has a self-loop: beg < end)
    int s0 = edge_src[beg];
    float as0 = a_s[s0 * 4 + head];
    uint2 v0 = *(const uint2*)&hh[(size_t)s0 * 256 + lane * 4];
    int s1 = s0; float as1 = as0; uint2 v1 = v0;
    if (beg + 1 < end) {
        s1 = edge_src[beg + 1];
        as1 = a_s[s1 * 4 + head];
        v1 = *(const uint2*)&hh[(size_t)s1 * 256 + lane * 4];
    }

    for (int i = beg; i < end; ++i) {
        int s2 = s1; float as2 = as1; uint2 v2 = v1;
        if (i + 2 < end) {
            s2 = edge_src[i + 2];
            as2 = a_s[s2 * 4 + head];
            v2 = *(const uint2*)&hh[(size_t)s2 * 256 + lane * 4];
        }
        float e = as0 + ad;
        e = (e > 0.f) ? e : LEAKY_SLOPE * e;
        float w = __expf(e);
        __half2 p = *(__half2*)&v0.x;
        __half2 q = *(__half2*)&v0.y;
        float2 f1 = __half22float2(p);
        float2 f2 = __half22float2(q);
        l += w;
        ax = fmaf(w, f1.x, ax);
        ay = fmaf(w, f1.y, ay);
        az = fmaf(w, f2.x, az);
        aw = fmaf(w, f2.y, aw);
        s0 = s1; as0 = as1; v0 = v1;
        s1 = s2; as1 = as2; v1 = v2;
    }

    float r = 1.f / l;
    float4 b4 = *(const float4*)&bias[lane * 4];
    float ox = fmaf(ax, r, b4.x);
    float oy = fmaf(ay, r, b4.y);
    float oz = fmaf(az, r, b4.z);
    float ow = fmaf(aw, r, b4.w);
    ox = (ox > 0.f) ? ox : __expf(ox) - 1.f;
    oy = (oy > 0.f) ? oy : __expf(oy) - 1.f;
    oz = (oz > 0.f) ? oz : __expf(oz) - 1.f;
    ow = (ow > 0.f) ? ow : __expf(ow) - 1.f;
    float4 o = {ox, oy, oz, ow};
    *(float4*)&out[(size_t)node * 256 + lane * 4] = o;
}

// ---------------- launch ----------------

extern "C" void kernel_launch(void* const* d_in, const int* in_sizes, int n_in,
                              void* d_out, int out_size, void* d_ws, size_t ws_size,
                              hipStream_t stream) {
    const float* x   = (const float*)d_in[0];
    const int*   ei  = (const int*)d_in[1];
    const float* W1  = (const float*)d_in[2];
    const float* as1 = (const float*)d_in[3];
    const float* ad1 = (const float*)d_in[4];
    const float* b1  = (const float*)d_in[5];
    const float* W2  = (const float*)d_in[6];
    const float* as2 = (const float*)d_in[7];
    const float* ad2 = (const float*)d_in[8];
    const float* b2  = (const float*)d_in[9];
    float* out = (float*)d_out;

    const int N = in_sizes[0] / 128;
    const int E = in_sizes[1] / 2;
    const int Etot = E + N;

    // workspace layout
    __half* h_half = (__half*)d_ws;                       // N*256 fp16
    float* x1_buf  = (float*)(h_half + (size_t)N * 256);  // N*256 fp32
    float* a_s     = x1_buf + (size_t)N * 256;            // N*4
    float* a_d     = a_s + (size_t)N * 4;                 // N*4
    int*   cnt     = (int*)(a_d + (size_t)N * 4);         // N
    int*   fill    = cnt + N;                             // N
    int*   row_st  = fill + N;                            // N+1
    int*   edge_src= row_st + (N + 1);                    // Etot

    hipMemsetAsync(cnt, 0, sizeof(int) * 2 * (size_t)N, stream);  // cnt + fill
    int eblocks = (Etot + 255) / 256;
    hist_kernel<<<eblocks, 256, 0, stream>>>(ei, cnt, E, Etot);
    scan_kernel<<<1, 1024, 0, stream>>>(cnt, row_st, N);
    scatter_kernel<<<eblocks, 256, 0, stream>>>(ei, row_st, fill, edge_src, E, Etot);

    dim3 ggrid(2 * ((N + 127) / 128));
    int nblocks = (N + 3) / 4;

    gemm_mfma<128><<<ggrid, 256, 0, stream>>>(x, W1, h_half, as1, ad1, a_s, a_d, N);
    gat_aggregate<<<nblocks, 256, 0, stream>>>(h_half, a_s, a_d, row_st, edge_src,
                                               b1, x1_buf, N);
    gemm_mfma<256><<<ggrid, 256, 0, stream>>>(x1_buf, W2, h_half, as2, ad2, a_s, a_d, N);
    gat_aggregate<<<nblocks, 256, 0, stream>>>(h_half, a_s, a_d, row_st, edge_src,
                                               b2, out, N);
}

// Round 4
// 409.602 us; speedup vs baseline: 1.8033x; 1.2530x over previous
//
#include <hip/hip_runtime.h>
#include <hip/hip_fp16.h>
#include <math.h>

// ---------------------------------------------------------------------------
// GAT encoder, 2 layers.
//   GEMMs: 2-term split-bf16 MFMA (A_hi(rne)*B_hi + A_hi*B_lo); epilogue
//          writes h in FP16 and computes per-head a_s/a_d from fp32 accs.
//   Aggregation: CSR-by-dst gather, 2 nodes per wave (32 lanes/node,
//   16B/lane uint4 gathers), lane-local softmax w/o running max,
//   2-deep prefetch per node stream (4 gathers in flight per wave).
// ---------------------------------------------------------------------------

#define LEAKY_SLOPE 0.2f

typedef __attribute__((ext_vector_type(8))) short short8v;   // 8 bf16
typedef __attribute__((ext_vector_type(4))) float float4v;

// ---------------- CSR build ----------------

__global__ void hist_kernel(const int* __restrict__ ei, int* __restrict__ cnt,
                            int E, int Etot) {
    int e = blockIdx.x * blockDim.x + threadIdx.x;
    if (e >= Etot) return;
    int dst = (e < E) ? ei[E + e] : (e - E);
    atomicAdd(&cnt[dst], 1);
}

// 3-kernel scan: per-block scan -> scan partials (1 wave) -> add offsets
__global__ __launch_bounds__(1024) void scan_block(const int* __restrict__ cnt,
                                                   int* __restrict__ row_start,
                                                   int* __restrict__ partials,
                                                   int n) {
    __shared__ int wsum[16];
    int tid = threadIdx.x, lane = tid & 63, wid = tid >> 6;
    int gi = blockIdx.x * 1024 + tid;
    int v = (gi < n) ? cnt[gi] : 0;
    int x = v;
#pragma unroll
    for (int off = 1; off < 64; off <<= 1) {
        int y = __shfl_up(x, off, 64);
        if (lane >= off) x += y;
    }
    if (lane == 63) wsum[wid] = x;
    __syncthreads();
    if (wid == 0 && lane < 16) {
        int w = wsum[lane];
#pragma unroll
        for (int off = 1; off < 16; off <<= 1) {
            int y = __shfl_up(w, off, 16);
            if (lane >= off) w += y;
        }
        wsum[lane] = w;
    }
    __syncthreads();
    int excl = x - v + ((wid > 0) ? wsum[wid - 1] : 0);
    if (gi < n) row_start[gi] = excl;
    if (tid == 1023) partials[blockIdx.x] = wsum[15];
}

__global__ void scan_partials(int* __restrict__ partials, int nb) {
    int lane = threadIdx.x;  // 64 threads, nb <= 64
    int v = (lane < nb) ? partials[lane] : 0;
    int x = v;
#pragma unroll
    for (int off = 1; off < 64; off <<= 1) {
        int y = __shfl_up(x, off, 64);
        if (lane >= off) x += y;
    }
    if (lane < nb) partials[lane] = x - v;      // exclusive
    if (lane == nb - 1) partials[nb] = x;       // total
}

__global__ __launch_bounds__(1024) void scan_add(int* __restrict__ row_start,
                                                 const int* __restrict__ partials,
                                                 int n, int nb) {
    int gi = blockIdx.x * 1024 + threadIdx.x;
    if (gi < n) row_start[gi] += partials[blockIdx.x];
    if (gi == 0) row_start[n] = partials[nb];
}

__global__ void scatter_kernel(const int* __restrict__ ei,
                               const int* __restrict__ row_start,
                               int* __restrict__ fill,
                               int* __restrict__ edge_src, int E, int Etot) {
    int e = blockIdx.x * blockDim.x + threadIdx.x;
    if (e >= Etot) return;
    int src, dst;
    if (e < E) { src = ei[e]; dst = ei[E + e]; }
    else       { src = e - E; dst = e - E; }
    int pos = row_start[dst] + atomicAdd(&fill[dst], 1);
    edge_src[pos] = src;
}

// ---------------- split-bf16 MFMA GEMM + fused attention dots ---------------
// C[M,256] = A[M,K] @ B[K,256], C stored fp16.
// 2-term: A_hi(rne) * (B_hi + B_lo). 128x128 tile, BK=32, 2x2 waves.

__device__ __forceinline__ short bf16_rne(float f) {
    unsigned u = __float_as_uint(f);
    return (short)((u + 0x7FFFu + ((u >> 16) & 1u)) >> 16);
}

__device__ __forceinline__ void split_bf16(float f, short& hi, short& lo) {
    unsigned u = __float_as_uint(f);
    hi = (short)(u >> 16);
    float fhi = __uint_as_float(u & 0xFFFF0000u);
    float flo = f - fhi;  // exact
    lo = (short)(__float_as_uint(flo) >> 16);
}

template <int K>
__global__ __launch_bounds__(256) void gemm_mfma(
    const float* __restrict__ A, const float* __restrict__ B,
    __half* __restrict__ Ch, const float* __restrict__ att_src,
    const float* __restrict__ att_dst, float* __restrict__ a_s_out,
    float* __restrict__ a_d_out, int M) {
    __shared__ short As_hi[128][40];   // [m][k], pad 32->40
    __shared__ short Bs_hi[128][40];   // [n][k] (transposed)
    __shared__ short Bs_lo[128][40];

    const int col0 = (blockIdx.x & 1) * 128;
    const int row0 = (blockIdx.x >> 1) * 128;
    const int tid = threadIdx.x;
    const int lane = tid & 63;
    const int wave = tid >> 6;
    const int wr = wave >> 1, wc = wave & 1;
    const int quad = lane >> 4, lc = lane & 15;

    float4v acc[4][4] = {};

    const int bn = tid & 127;
    const int bkh = (tid >> 7) * 16;

    for (int k0 = 0; k0 < K; k0 += 32) {
#pragma unroll
        for (int i = 0; i < 4; i++) {
            int slot = tid + i * 256;
            int r = slot >> 3;
            int kq = (slot & 7) * 4;
            float4 v = {0.f, 0.f, 0.f, 0.f};
            int gr = row0 + r;
            if (gr < M) v = *(const float4*)&A[(size_t)gr * K + k0 + kq];
            short4 h4;
            h4.x = bf16_rne(v.x); h4.y = bf16_rne(v.y);
            h4.z = bf16_rne(v.z); h4.w = bf16_rne(v.w);
            *(short4*)&As_hi[r][kq] = h4;
        }
        {
            float f[16];
#pragma unroll
            for (int j = 0; j < 16; j++)
                f[j] = B[(size_t)(k0 + bkh + j) * 256 + col0 + bn];
            short h8[16], l8[16];
#pragma unroll
            for (int j = 0; j < 16; j++) split_bf16(f[j], h8[j], l8[j]);
#pragma unroll
            for (int j = 0; j < 4; j++) {
                *(short4*)&Bs_hi[bn][bkh + j * 4] = *(short4*)&h8[j * 4];
                *(short4*)&Bs_lo[bn][bkh + j * 4] = *(short4*)&l8[j * 4];
            }
        }
        __syncthreads();

        short8v a_hi[4], b_hi[4], b_lo[4];
#pragma unroll
        for (int mt = 0; mt < 4; mt++) {
            int r = wr * 64 + mt * 16 + lc;
            a_hi[mt] = *(const short8v*)&As_hi[r][quad * 8];
        }
#pragma unroll
        for (int nt = 0; nt < 4; nt++) {
            int n = wc * 64 + nt * 16 + lc;
            b_hi[nt] = *(const short8v*)&Bs_hi[n][quad * 8];
            b_lo[nt] = *(const short8v*)&Bs_lo[n][quad * 8];
        }
#pragma unroll
        for (int mt = 0; mt < 4; mt++)
#pragma unroll
            for (int nt = 0; nt < 4; nt++) {
                acc[mt][nt] = __builtin_amdgcn_mfma_f32_16x16x32_bf16(
                    a_hi[mt], b_hi[nt], acc[mt][nt], 0, 0, 0);
                acc[mt][nt] = __builtin_amdgcn_mfma_f32_16x16x32_bf16(
                    a_hi[mt], b_lo[nt], acc[mt][nt], 0, 0, 0);
            }
        __syncthreads();
    }

    // ---- epilogue: wave's 64 cols = head; C/D: col=lc(+nt*16), row=quad*4+r
    const int head = (col0 >> 6) + wc;
    float as_c[4], ad_c[4];
#pragma unroll
    for (int nt = 0; nt < 4; nt++) {
        as_c[nt] = att_src[head * 64 + nt * 16 + lc];
        ad_c[nt] = att_dst[head * 64 + nt * 16 + lc];
    }

#pragma unroll
    for (int mt = 0; mt < 4; mt++) {
#pragma unroll
        for (int r = 0; r < 4; r++) {
            int gr = row0 + wr * 64 + mt * 16 + quad * 4 + r;
            float ps = 0.f, pd = 0.f;
#pragma unroll
            for (int nt = 0; nt < 4; nt++) {
                float c = acc[mt][nt][r];
                ps = fmaf(c, as_c[nt], ps);
                pd = fmaf(c, ad_c[nt], pd);
                if (gr < M)
                    Ch[(size_t)gr * 256 + col0 + wc * 64 + nt * 16 + lc] =
                        __float2half(c);
            }
#pragma unroll
            for (int off = 1; off < 16; off <<= 1) {
                ps += __shfl_xor(ps, off, 64);
                pd += __shfl_xor(pd, off, 64);
            }
            if (lc == 0 && gr < M) {
                a_s_out[gr * 4 + head] = ps;
                a_d_out[gr * 4 + head] = pd;
            }
        }
    }
}

// ---------------- fused softmax + aggregate + bias + elu ----------------
// 2 nodes per wave: half-wave (32 lanes) per node, lane covers 8 channels
// (16B fp16 = uint4). head = l32>>3, channel offset = l32*8 within the row.

__global__ __launch_bounds__(256) void gat_aggregate(
    const __half* __restrict__ hh, const float* __restrict__ a_s,
    const float* __restrict__ a_d, const int* __restrict__ row_start,
    const int* __restrict__ edge_src, const float* __restrict__ bias,
    float* __restrict__ out, int n) {
    int wid = (blockIdx.x * blockDim.x + threadIdx.x) >> 6;
    int lane = threadIdx.x & 63;
    int half = lane >> 5, l32 = lane & 31;
    int node = wid * 2 + half;
    bool valid = (node < n);
    int nd = valid ? node : 0;
    int head = l32 >> 3;

    float ad = a_d[nd * 4 + head];
    int beg = row_start[nd];
    int end = valid ? row_start[nd + 1] : beg;

    float l = 0.f;
    float acc[8] = {};

    int s0 = 0, s1 = 0;
    float as0 = 0.f, as1 = 0.f;
    uint4 v0 = {0, 0, 0, 0}, v1 = {0, 0, 0, 0};
    if (beg < end) {
        s0 = edge_src[beg];
        as0 = a_s[s0 * 4 + head];
        v0 = *(const uint4*)&hh[(size_t)s0 * 256 + l32 * 8];
    }
    if (beg + 1 < end) {
        s1 = edge_src[beg + 1];
        as1 = a_s[s1 * 4 + head];
        v1 = *(const uint4*)&hh[(size_t)s1 * 256 + l32 * 8];
    }

    for (int i = beg; i < end; ++i) {
        int s2 = s1; float as2 = as1; uint4 v2 = v1;
        if (i + 2 < end) {
            s2 = edge_src[i + 2];
            as2 = a_s[s2 * 4 + head];
            v2 = *(const uint4*)&hh[(size_t)s2 * 256 + l32 * 8];
        }
        float e = as0 + ad;
        e = (e > 0.f) ? e : LEAKY_SLOPE * e;
        float w = __expf(e);
        l += w;
        const __half2* hp = (const __half2*)&v0;
#pragma unroll
        for (int j = 0; j < 4; j++) {
            float2 f = __half22float2(hp[j]);
            acc[2 * j]     = fmaf(w, f.x, acc[2 * j]);
            acc[2 * j + 1] = fmaf(w, f.y, acc[2 * j + 1]);
        }
        s0 = s1; as0 = as1; v0 = v1;
        s1 = s2; as1 = as2; v1 = v2;
    }

    if (valid) {
        float r = 1.f / l;
        float4 b0 = *(const float4*)&bias[l32 * 8];
        float4 b1 = *(const float4*)&bias[l32 * 8 + 4];
        float o[8];
        const float* bb = &b0.x;
        o[0] = fmaf(acc[0], r, b0.x); o[1] = fmaf(acc[1], r, b0.y);
        o[2] = fmaf(acc[2], r, b0.z); o[3] = fmaf(acc[3], r, b0.w);
        o[4] = fmaf(acc[4], r, b1.x); o[5] = fmaf(acc[5], r, b1.y);
        o[6] = fmaf(acc[6], r, b1.z); o[7] = fmaf(acc[7], r, b1.w);
        (void)bb;
#pragma unroll
        for (int j = 0; j < 8; j++)
            o[j] = (o[j] > 0.f) ? o[j] : __expf(o[j]) - 1.f;
        *(float4*)&out[(size_t)node * 256 + l32 * 8]     = *(float4*)&o[0];
        *(float4*)&out[(size_t)node * 256 + l32 * 8 + 4] = *(float4*)&o[4];
    }
}

// ---------------- launch ----------------

extern "C" void kernel_launch(void* const* d_in, const int* in_sizes, int n_in,
                              void* d_out, int out_size, void* d_ws, size_t ws_size,
                              hipStream_t stream) {
    const float* x   = (const float*)d_in[0];
    const int*   ei  = (const int*)d_in[1];
    const float* W1  = (const float*)d_in[2];
    const float* as1 = (const float*)d_in[3];
    const float* ad1 = (const float*)d_in[4];
    const float* b1  = (const float*)d_in[5];
    const float* W2  = (const float*)d_in[6];
    const float* as2 = (const float*)d_in[7];
    const float* ad2 = (const float*)d_in[8];
    const float* b2  = (const float*)d_in[9];
    float* out = (float*)d_out;

    const int N = in_sizes[0] / 128;
    const int E = in_sizes[1] / 2;
    const int Etot = E + N;
    const int NB = (N + 1023) / 1024;   // scan blocks (<= 64)

    // workspace layout
    __half* h_half = (__half*)d_ws;                       // N*256 fp16
    float* x1_buf  = (float*)(h_half + (size_t)N * 256);  // N*256 fp32
    float* a_s     = x1_buf + (size_t)N * 256;            // N*4
    float* a_d     = a_s + (size_t)N * 4;                 // N*4
    int*   cnt     = (int*)(a_d + (size_t)N * 4);         // N
    int*   fill    = cnt + N;                             // N
    int*   row_st  = fill + N;                            // N+1
    int*   edge_src= row_st + (N + 1);                    // Etot
    int*   partials= edge_src + Etot;                     // NB+1

    hipMemsetAsync(cnt, 0, sizeof(int) * 2 * (size_t)N, stream);  // cnt + fill
    int eblocks = (Etot + 255) / 256;
    hist_kernel<<<eblocks, 256, 0, stream>>>(ei, cnt, E, Etot);
    scan_block<<<NB, 1024, 0, stream>>>(cnt, row_st, partials, N);
    scan_partials<<<1, 64, 0, stream>>>(partials, NB);
    scan_add<<<NB, 1024, 0, stream>>>(row_st, partials, N, NB);
    scatter_kernel<<<eblocks, 256, 0, stream>>>(ei, row_st, fill, edge_src, E, Etot);

    dim3 ggrid(2 * ((N + 127) / 128));
    int ablocks = (N + 7) / 8;   // 8 nodes per 256-thread block

    gemm_mfma<128><<<ggrid, 256, 0, stream>>>(x, W1, h_half, as1, ad1, a_s, a_d, N);
    gat_aggregate<<<ablocks, 256, 0, stream>>>(h_half, a_s, a_d, row_st, edge_src,
                                               b1, x1_buf, N);
    gemm_mfma<256><<<ggrid, 256, 0, stream>>>(x1_buf, W2, h_half, as2, ad2, a_s, a_d, N);
    gat_aggregate<<<ablocks, 256, 0, stream>>>(h_half, a_s, a_d, row_st, edge_src,
                                               b2, out, N);
}

// Round 5
// 396.168 us; speedup vs baseline: 1.8645x; 1.0339x over previous
//
#include <hip/hip_runtime.h>
#include <hip/hip_fp16.h>
#include <math.h>

// ---------------------------------------------------------------------------
// GAT encoder, 2 layers.
//   GEMMs: 2-term split-bf16 MFMA (A_hi(rne)*B_hi + A_hi*B_lo); epilogue
//          writes h in FP16 and per-head a_s (fp16) / a_d (fp32).
//   Layer-1 output x1 stored bf16-rne (identical input to the 2-term GEMM).
//   Aggregation: per-layer edge-record stream {src, a_s[src] fp16x4} (16B,
//   sequential broadcast load) + one random fp16 h-row gather per edge;
//   2 nodes/wave, depth-3 rotation-free software pipeline.
// ---------------------------------------------------------------------------

#define LEAKY_SLOPE 0.2f

typedef __attribute__((ext_vector_type(8))) short short8v;   // 8 bf16
typedef __attribute__((ext_vector_type(4))) float float4v;

// ---------------- CSR build ----------------

__global__ void hist_kernel(const int* __restrict__ ei, int* __restrict__ cnt,
                            int E, int Etot) {
    int e = blockIdx.x * blockDim.x + threadIdx.x;
    if (e >= Etot) return;
    int dst = (e < E) ? ei[E + e] : (e - E);
    atomicAdd(&cnt[dst], 1);
}

__global__ __launch_bounds__(1024) void scan_block(const int* __restrict__ cnt,
                                                   int* __restrict__ row_start,
                                                   int* __restrict__ partials,
                                                   int n) {
    __shared__ int wsum[16];
    int tid = threadIdx.x, lane = tid & 63, wid = tid >> 6;
    int gi = blockIdx.x * 1024 + tid;
    int v = (gi < n) ? cnt[gi] : 0;
    int x = v;
#pragma unroll
    for (int off = 1; off < 64; off <<= 1) {
        int y = __shfl_up(x, off, 64);
        if (lane >= off) x += y;
    }
    if (lane == 63) wsum[wid] = x;
    __syncthreads();
    if (wid == 0 && lane < 16) {
        int w = wsum[lane];
#pragma unroll
        for (int off = 1; off < 16; off <<= 1) {
            int y = __shfl_up(w, off, 16);
            if (lane >= off) w += y;
        }
        wsum[lane] = w;
    }
    __syncthreads();
    int excl = x - v + ((wid > 0) ? wsum[wid - 1] : 0);
    if (gi < n) row_start[gi] = excl;
    if (tid == 1023) partials[blockIdx.x] = wsum[15];
}

__global__ void scan_partials(int* __restrict__ partials, int nb) {
    int lane = threadIdx.x;  // 64 threads, nb <= 64
    int v = (lane < nb) ? partials[lane] : 0;
    int x = v;
#pragma unroll
    for (int off = 1; off < 64; off <<= 1) {
        int y = __shfl_up(x, off, 64);
        if (lane >= off) x += y;
    }
    if (lane < nb) partials[lane] = x - v;
    if (lane == nb - 1) partials[nb] = x;
}

__global__ __launch_bounds__(1024) void scan_add(int* __restrict__ row_start,
                                                 const int* __restrict__ partials,
                                                 int n, int nb) {
    int gi = blockIdx.x * 1024 + threadIdx.x;
    if (gi < n) row_start[gi] += partials[blockIdx.x];
    if (gi == 0) row_start[n] = partials[nb];
}

__global__ void scatter_kernel(const int* __restrict__ ei,
                               const int* __restrict__ row_start,
                               int* __restrict__ fill,
                               int* __restrict__ edge_src, int E, int Etot) {
    int e = blockIdx.x * blockDim.x + threadIdx.x;
    if (e >= Etot) return;
    int src, dst;
    if (e < E) { src = ei[e]; dst = ei[E + e]; }
    else       { src = e - E; dst = e - E; }
    int pos = row_start[dst] + atomicAdd(&fill[dst], 1);
    edge_src[pos] = src;
}

// per-layer: rec[i] = {src, a_s[src] as 4 x fp16, pad}
__global__ void fill_rec(const int* __restrict__ edge_src,
                         const __half* __restrict__ a_s_h,
                         uint4* __restrict__ rec, int Etot) {
    int i = blockIdx.x * blockDim.x + threadIdx.x;
    if (i >= Etot) return;
    int s = edge_src[i];
    uint2 as8 = *(const uint2*)&a_s_h[(size_t)s * 4];
    uint4 r = {(unsigned)s, as8.x, as8.y, 0u};
    rec[i] = r;
}

// ---------------- split-bf16 MFMA GEMM + fused attention dots ---------------
// C[M,256] = A[M,K] @ B[K,256], C stored fp16. A fp32 (split-rne) or bf16.
// 2-term: A_hi(rne) * (B_hi + B_lo). 128x128 tile, BK=32, 2x2 waves.

__device__ __forceinline__ short bf16_rne(float f) {
    unsigned u = __float_as_uint(f);
    return (short)((u + 0x7FFFu + ((u >> 16) & 1u)) >> 16);
}

__device__ __forceinline__ void split_bf16(float f, short& hi, short& lo) {
    unsigned u = __float_as_uint(f);
    hi = (short)(u >> 16);
    float fhi = __uint_as_float(u & 0xFFFF0000u);
    float flo = f - fhi;  // exact
    lo = (short)(__float_as_uint(flo) >> 16);
}

template <int K, bool ABF16>
__global__ __launch_bounds__(256) void gemm_mfma(
    const void* __restrict__ Ap, const float* __restrict__ B,
    __half* __restrict__ Ch, const float* __restrict__ att_src,
    const float* __restrict__ att_dst, __half* __restrict__ a_s_out,
    float* __restrict__ a_d_out, int M) {
    __shared__ short As_hi[128][40];   // [m][k], pad 32->40
    __shared__ short Bs_hi[128][40];   // [n][k] (transposed)
    __shared__ short Bs_lo[128][40];

    const int col0 = (blockIdx.x & 1) * 128;
    const int row0 = (blockIdx.x >> 1) * 128;
    const int tid = threadIdx.x;
    const int lane = tid & 63;
    const int wave = tid >> 6;
    const int wr = wave >> 1, wc = wave & 1;
    const int quad = lane >> 4, lc = lane & 15;

    float4v acc[4][4] = {};

    const int bn = tid & 127;
    const int bkh = (tid >> 7) * 16;

    for (int k0 = 0; k0 < K; k0 += 32) {
        if constexpr (ABF16) {
            const short* Abf = (const short*)Ap;
#pragma unroll
            for (int i = 0; i < 2; i++) {
                int slot = tid + i * 256;       // 0..511
                int r = slot >> 2;              // 0..127
                int ko = (slot & 3) * 8;        // 0,8,16,24
                short8v v = {};
                int gr = row0 + r;
                if (gr < M) v = *(const short8v*)&Abf[(size_t)gr * K + k0 + ko];
                short4 lo4 = {v[0], v[1], v[2], v[3]};
                short4 hi4 = {v[4], v[5], v[6], v[7]};
                *(short4*)&As_hi[r][ko] = lo4;
                *(short4*)&As_hi[r][ko + 4] = hi4;
            }
        } else {
            const float* A = (const float*)Ap;
#pragma unroll
            for (int i = 0; i < 4; i++) {
                int slot = tid + i * 256;
                int r = slot >> 3;
                int kq = (slot & 7) * 4;
                float4 v = {0.f, 0.f, 0.f, 0.f};
                int gr = row0 + r;
                if (gr < M) v = *(const float4*)&A[(size_t)gr * K + k0 + kq];
                short4 h4;
                h4.x = bf16_rne(v.x); h4.y = bf16_rne(v.y);
                h4.z = bf16_rne(v.z); h4.w = bf16_rne(v.w);
                *(short4*)&As_hi[r][kq] = h4;
            }
        }
        {
            float f[16];
#pragma unroll
            for (int j = 0; j < 16; j++)
                f[j] = B[(size_t)(k0 + bkh + j) * 256 + col0 + bn];
            short h8[16], l8[16];
#pragma unroll
            for (int j = 0; j < 16; j++) split_bf16(f[j], h8[j], l8[j]);
#pragma unroll
            for (int j = 0; j < 4; j++) {
                *(short4*)&Bs_hi[bn][bkh + j * 4] = *(short4*)&h8[j * 4];
                *(short4*)&Bs_lo[bn][bkh + j * 4] = *(short4*)&l8[j * 4];
            }
        }
        __syncthreads();

        short8v a_hi[4], b_hi[4], b_lo[4];
#pragma unroll
        for (int mt = 0; mt < 4; mt++) {
            int r = wr * 64 + mt * 16 + lc;
            a_hi[mt] = *(const short8v*)&As_hi[r][quad * 8];
        }
#pragma unroll
        for (int nt = 0; nt < 4; nt++) {
            int n = wc * 64 + nt * 16 + lc;
            b_hi[nt] = *(const short8v*)&Bs_hi[n][quad * 8];
            b_lo[nt] = *(const short8v*)&Bs_lo[n][quad * 8];
        }
#pragma unroll
        for (int mt = 0; mt < 4; mt++)
#pragma unroll
            for (int nt = 0; nt < 4; nt++) {
                acc[mt][nt] = __builtin_amdgcn_mfma_f32_16x16x32_bf16(
                    a_hi[mt], b_hi[nt], acc[mt][nt], 0, 0, 0);
                acc[mt][nt] = __builtin_amdgcn_mfma_f32_16x16x32_bf16(
                    a_hi[mt], b_lo[nt], acc[mt][nt], 0, 0, 0);
            }
        __syncthreads();
    }

    // ---- epilogue: wave's 64 cols = head; C/D: col=lc(+nt*16), row=quad*4+r
    const int head = (col0 >> 6) + wc;
    float as_c[4], ad_c[4];
#pragma unroll
    for (int nt = 0; nt < 4; nt++) {
        as_c[nt] = att_src[head * 64 + nt * 16 + lc];
        ad_c[nt] = att_dst[head * 64 + nt * 16 + lc];
    }

#pragma unroll
    for (int mt = 0; mt < 4; mt++) {
#pragma unroll
        for (int r = 0; r < 4; r++) {
            int gr = row0 + wr * 64 + mt * 16 + quad * 4 + r;
            float ps = 0.f, pd = 0.f;
#pragma unroll
            for (int nt = 0; nt < 4; nt++) {
                float c = acc[mt][nt][r];
                ps = fmaf(c, as_c[nt], ps);
                pd = fmaf(c, ad_c[nt], pd);
                if (gr < M)
                    Ch[(size_t)gr * 256 + col0 + wc * 64 + nt * 16 + lc] =
                        __float2half(c);
            }
#pragma unroll
            for (int off = 1; off < 16; off <<= 1) {
                ps += __shfl_xor(ps, off, 64);
                pd += __shfl_xor(pd, off, 64);
            }
            if (lc == 0 && gr < M) {
                a_s_out[gr * 4 + head] = __float2half(ps);
                a_d_out[gr * 4 + head] = pd;
            }
        }
    }
}

// ---------------- fused softmax + aggregate + bias + elu ----------------
// 2 nodes/wave (32 lanes/node, 16B/lane gathers). Depth-3 pipeline, no movs:
// at slot s: issue h(s+2) from rec slot, process (rec(s), h(s)), load rec(s+3).

template <bool OUT_BF16>
__global__ __launch_bounds__(256) void gat_aggregate(
    const __half* __restrict__ hh, const uint4* __restrict__ rec,
    const float* __restrict__ a_d, const int* __restrict__ row_start,
    const float* __restrict__ bias, void* __restrict__ outp, int n) {
    int wid = (blockIdx.x * blockDim.x + threadIdx.x) >> 6;
    int lane = threadIdx.x & 63;
    int half = lane >> 5, l32 = lane & 31;
    int node = wid * 2 + half;
    bool valid = (node < n);
    int nd = valid ? node : 0;
    int head = l32 >> 3;

    float ad = a_d[nd * 4 + head];
    int beg = row_start[nd];
    int end = valid ? row_start[nd + 1] : beg;

    float l = 0.f;
    float acc[8] = {};

    int em1 = (end > beg) ? (end - 1) : beg;
    uint4 r0 = rec[beg];
    uint4 r1 = rec[min(beg + 1, em1)];
    uint4 r2 = rec[min(beg + 2, em1)];

#define GATH(rr) (*(const uint4*)&hh[(size_t)(rr).x * 256 + l32 * 8])
#define PROC(rr, vv)                                                      \
    {                                                                     \
        unsigned u = (head & 2) ? (rr).z : (rr).y;                        \
        unsigned short us = (head & 1) ? (unsigned short)(u >> 16)        \
                                       : (unsigned short)(u & 0xFFFFu);   \
        float as = __half2float(*(const __half*)&us);                     \
        float e = as + ad;                                                \
        e = (e > 0.f) ? e : LEAKY_SLOPE * e;                              \
        float w = __expf(e);                                              \
        l += w;                                                           \
        const __half2* hp = (const __half2*)&(vv);                        \
        _Pragma("unroll") for (int j = 0; j < 4; j++) {                   \
            float2 f = __half22float2(hp[j]);                             \
            acc[2 * j] = fmaf(w, f.x, acc[2 * j]);                        \
            acc[2 * j + 1] = fmaf(w, f.y, acc[2 * j + 1]);                \
        }                                                                 \
    }

    uint4 h0 = GATH(r0);
    uint4 h1 = GATH(r1);
    uint4 h2;

    int s = beg;
    while (s < end) {
        // k = 0 : slot s
        h2 = GATH(r2);
        PROC(r0, h0);
        r0 = rec[min(s + 3, em1)];
        if (++s >= end) break;
        // k = 1
        h0 = GATH(r0);
        PROC(r1, h1);
        r1 = rec[min(s + 3, em1)];
        if (++s >= end) break;
        // k = 2
        h1 = GATH(r1);
        PROC(r2, h2);
        r2 = rec[min(s + 3, em1)];
        ++s;
    }
#undef GATH
#undef PROC

    if (valid) {
        float r = 1.f / l;
        float4 b0 = *(const float4*)&bias[l32 * 8];
        float4 b1 = *(const float4*)&bias[l32 * 8 + 4];
        float o[8];
        o[0] = fmaf(acc[0], r, b0.x); o[1] = fmaf(acc[1], r, b0.y);
        o[2] = fmaf(acc[2], r, b0.z); o[3] = fmaf(acc[3], r, b0.w);
        o[4] = fmaf(acc[4], r, b1.x); o[5] = fmaf(acc[5], r, b1.y);
        o[6] = fmaf(acc[6], r, b1.z); o[7] = fmaf(acc[7], r, b1.w);
#pragma unroll
        for (int j = 0; j < 8; j++)
            o[j] = (o[j] > 0.f) ? o[j] : __expf(o[j]) - 1.f;
        if constexpr (OUT_BF16) {
            short ob[8];
#pragma unroll
            for (int j = 0; j < 8; j++) ob[j] = bf16_rne(o[j]);
            short* outb = (short*)outp;
            *(short4*)&outb[(size_t)node * 256 + l32 * 8] = *(short4*)&ob[0];
            *(short4*)&outb[(size_t)node * 256 + l32 * 8 + 4] = *(short4*)&ob[4];
        } else {
            float* outf = (float*)outp;
            *(float4*)&outf[(size_t)node * 256 + l32 * 8] = *(float4*)&o[0];
            *(float4*)&outf[(size_t)node * 256 + l32 * 8 + 4] = *(float4*)&o[4];
        }
    }
}

// ---------------- launch ----------------

extern "C" void kernel_launch(void* const* d_in, const int* in_sizes, int n_in,
                              void* d_out, int out_size, void* d_ws, size_t ws_size,
                              hipStream_t stream) {
    const float* x   = (const float*)d_in[0];
    const int*   ei  = (const int*)d_in[1];
    const float* W1  = (const float*)d_in[2];
    const float* as1 = (const float*)d_in[3];
    const float* ad1 = (const float*)d_in[4];
    const float* b1  = (const float*)d_in[5];
    const float* W2  = (const float*)d_in[6];
    const float* as2 = (const float*)d_in[7];
    const float* ad2 = (const float*)d_in[8];
    const float* b2  = (const float*)d_in[9];
    float* out = (float*)d_out;

    const int N = in_sizes[0] / 128;
    const int E = in_sizes[1] / 2;
    const int Etot = E + N;
    const int NB = (N + 1023) / 1024;   // scan blocks (<= 64)

    // workspace layout (16B-aligned segments first)
    __half* h_half = (__half*)d_ws;                        // N*256 fp16
    short*  x1_bf  = (short*)(h_half + (size_t)N * 256);   // N*256 bf16
    uint4*  rec    = (uint4*)(x1_bf + (size_t)N * 256);    // Etot x 16B
    __half* a_s_h  = (__half*)(rec + Etot);                // N*4 fp16
    float*  a_d    = (float*)(a_s_h + (size_t)N * 4);      // N*4 fp32
    int*    cnt    = (int*)(a_d + (size_t)N * 4);          // N
    int*    fill   = cnt + N;                              // N
    int*    row_st = fill + N;                             // N+1
    int*    edge_src = row_st + (N + 1);                   // Etot
    int*    partials = edge_src + Etot;                    // NB+1

    hipMemsetAsync(cnt, 0, sizeof(int) * 2 * (size_t)N, stream);  // cnt + fill
    int eblocks = (Etot + 255) / 256;
    hist_kernel<<<eblocks, 256, 0, stream>>>(ei, cnt, E, Etot);
    scan_block<<<NB, 1024, 0, stream>>>(cnt, row_st, partials, N);
    scan_partials<<<1, 64, 0, stream>>>(partials, NB);
    scan_add<<<NB, 1024, 0, stream>>>(row_st, partials, N, NB);
    scatter_kernel<<<eblocks, 256, 0, stream>>>(ei, row_st, fill, edge_src, E, Etot);

    dim3 ggrid(2 * ((N + 127) / 128));
    int ablocks = (N + 7) / 8;   // 8 nodes per 256-thread block

    // layer 1
    gemm_mfma<128, false><<<ggrid, 256, 0, stream>>>(x, W1, h_half, as1, ad1,
                                                     a_s_h, a_d, N);
    fill_rec<<<eblocks, 256, 0, stream>>>(edge_src, a_s_h, rec, Etot);
    gat_aggregate<true><<<ablocks, 256, 0, stream>>>(h_half, rec, a_d, row_st,
                                                     b1, x1_bf, N);
    // layer 2
    gemm_mfma<256, true><<<ggrid, 256, 0, stream>>>(x1_bf, W2, h_half, as2, ad2,
                                                    a_s_h, a_d, N);
    fill_rec<<<eblocks, 256, 0, stream>>>(edge_src, a_s_h, rec, Etot);
    gat_aggregate<false><<<ablocks, 256, 0, stream>>>(h_half, rec, a_d, row_st,
                                                      b2, out, N);
}